// Round 11
// baseline (63.979 us; speedup 1.0000x reference)
//
#include <hip/hip_runtime.h>
#include <math.h>

// Problem geometry (fixed by reference)
#define BATCH   4096
#define NVARS   1024
#define ROWS_P0 8192
#define ROWS_S1 4096
#define ROWS_P2 8192
#define ROWS_S3 2048
#define ENCROWS 2050
#define ENCSTRIDE 2052   // uint2 rows per column-group (16B-aligned stride)

#define LOG2E 1.4426950408889634f
#define LN2   0.6931471805599453f

typedef _Float16 h4 __attribute__((ext_vector_type(4)));
typedef float    f2 __attribute__((ext_vector_type(2)));

union HU { h4 h; uint2 u; };

__device__ __forceinline__ float log1mexp_f(float x) {
    // accurate log(1 - exp(x)) for x < 0 (Maechler 2012) — libm for precision near 0-
    if (x > -0.6931471805599453f) return logf(-expm1f(x));
    return log1pf(-expf(x));
}

__device__ __forceinline__ float fexp2(float x) { return __builtin_amdgcn_exp2f(x); }
__device__ __forceinline__ float flog2(float x) { return __builtin_amdgcn_logf(x); }

// Pack two positive f32 (<=1.0) -> bf16x2 in one u32, round-half-up (5 VALU ops).
__device__ __forceinline__ unsigned pk_bf16(float x, float y) {
    unsigned xb = __float_as_uint(x) + 0x8000u;
    unsigned yb = __float_as_uint(y) + 0x8000u;
    return (xb >> 16) | (yb & 0xFFFF0000u);
}
__device__ __forceinline__ float bf_lo(unsigned v) { return __uint_as_float(v << 16); }
__device__ __forceinline__ float bf_hi(unsigned v) { return __uint_as_float(v & 0xFFFF0000u); }
__device__ __forceinline__ f2 mk2(float a, float b) { f2 r; r.x = a; r.y = b; return r; }

// ---------------- fused transpose+encode: pos[1024][4096] -> enc_t[1024 cg][2052] uint2 ----------------
// Moves ALL log1mexp libm work into this memory-bound kernel (VALU here is free).
// enc_t row layout per column-group cg (4 batch columns): row 0 = -inf x4, row 1 = 0 x4,
// row 2+2v = pos*log2e (h4), row 3+2v = log1mexp(pos)*log2e (h4) — exactly the pipeline's
// LDS enc table, so the pipeline's E phase is a straight coalesced copy.
__global__ __launch_bounds__(256) void encode_kernel(const float* __restrict__ pos,
                                                     uint2* __restrict__ enc_t) {
    __shared__ float tile[32][33];
    int bx = blockIdx.x;  // batch tile (128 tiles of 32 columns)
    int by = blockIdx.y;  // var tile (32 tiles of 32 vars)
    int tx = threadIdx.x, ty = threadIdx.y;  // block (32, 8)
    int c = bx * 32 + tx;
#pragma unroll
    for (int i = 0; i < 4; ++i) {
        int v = by * 32 + ty + i * 8;
        tile[ty + i * 8][tx] = pos[(size_t)v * BATCH + c];
    }
    __syncthreads();
    int t = ty * 32 + tx;      // 0..255
    int cgl = t & 7;           // local column-group 0..7
    int vv = t >> 3;           // local var 0..31
    int v = by * 32 + vv;
    int cg = bx * 8 + cgl;
    float a0 = tile[vv][cgl * 4 + 0];
    float a1 = tile[vv][cgl * 4 + 1];
    float a2 = tile[vv][cgl * 4 + 2];
    float a3 = tile[vv][cgl * 4 + 3];
    HU ep, en;
    ep.h.x = (_Float16)(a0 * LOG2E); ep.h.y = (_Float16)(a1 * LOG2E);
    ep.h.z = (_Float16)(a2 * LOG2E); ep.h.w = (_Float16)(a3 * LOG2E);
    en.h.x = (_Float16)(log1mexp_f(a0) * LOG2E); en.h.y = (_Float16)(log1mexp_f(a1) * LOG2E);
    en.h.z = (_Float16)(log1mexp_f(a2) * LOG2E); en.h.w = (_Float16)(log1mexp_f(a3) * LOG2E);
    uint2* dst = enc_t + (size_t)cg * ENCSTRIDE;
    dst[2 + 2 * v] = ep.u;
    dst[3 + 2 * v] = en.u;
    if (by == 0 && vv == 0) {  // 8 threads (one per cg) write header rows
        HU ni, z;
        ni.h.x = ni.h.y = ni.h.z = ni.h.w = (_Float16)(-INFINITY);  // row 0: never gathered (idx0>=1)
        z.h.x = z.h.y = z.h.z = z.h.w = (_Float16)0.f;              // row 1: log(1)
        dst[0] = ni.u;
        dst[1] = z.u;
    }
}

// ---------------- whole-circuit persistent kernel: one block = 4 batch columns ----------------
// Structure as round 9 (packed math, register-deferred tables, 64 KiB LDS -> 2 blocks/CU,
// all-b64 LDS gathers, bijective XCD-chunked swizzle for write-combining).
// Round-10 change: E phase is a coalesced copy of the precomputed enc_t column-group.
// Round-10 BUG FIX: the copy must cover ALL 2050 rows — previous version missed rows
// 2048-2049 (var 1023), reading poisoned LDS -> inf. Now: 2 full passes + 2-thread tail.
//   enc : h4[2050]    log2-domain f16x4   | p0/p2 : uint2[8192] EXP2-domain bf16x4
//   s1  : h4[4096]    log2-domain f16x4   (tables overlay one another phase by phase)
// No max-subtraction: p0 in 2^[-80,0], realistic p2 >= 2^-110 > bf16 min-normal.
// fmax floors never trigger legitimately; they only stop pathological 0 -> -inf/NaN.
__global__ __launch_bounds__(1024, 8) void pipeline_kernel(const uint2* __restrict__ enc_t,  // [1024][2052]
                                                           const int4* __restrict__ idx0,    // [8192]
                                                           const int4* __restrict__ idx1,    // [4096][2]
                                                           const int4* __restrict__ idx2,    // [8192]
                                                           const int4* __restrict__ idx3,    // [2048][2]
                                                           float* __restrict__ out) {        // [2048][4096]
    __shared__ __align__(16) char pool[65536];
    h4*    enc = reinterpret_cast<h4*>(pool);      // [2050]  (16400 B)
    uint2* p0  = reinterpret_cast<uint2*>(pool);   // [8192]  (65536 B)
    h4*    s1  = reinterpret_cast<h4*>(pool);      // [4096]  (32768 B)
    uint2* p2  = reinterpret_cast<uint2*>(pool);   // [8192]  (65536 B)

    const int tid = threadIdx.x;
    // XCD-chunked bijective swizzle: 1024 blocks, 8 XCDs, 128 blocks/XCD chunk.
    const int bid = blockIdx.x;
    const int swz = ((bid & 7) << 7) | (bid >> 3);

    // ---- E: coalesced copy of precomputed enc column-group into LDS (ALL 2050 rows) ----
    {
        const uint2* src = enc_t + (size_t)swz * ENCSTRIDE;
        uint2* encu = reinterpret_cast<uint2*>(pool);
        encu[tid] = src[tid];                              // rows    0..1023
        encu[1024 + tid] = src[1024 + tid];                // rows 1024..2047
        if (tid < ENCROWS - 2048) encu[2048 + tid] = src[2048 + tid];  // rows 2048..2049
    }
    __syncthreads();

    // ---- P0: gather-4 from enc (b64), packed-f16 sum tree, 2^x, hold bf16x4 in regs ----
    uint2 hold0[8];
#pragma unroll
    for (int i = 0; i < ROWS_P0 / 1024; ++i) {
        int r = tid + i * 1024;
        int4 ix = idx0[r];
        h4 v0 = enc[ix.x], v1 = enc[ix.y], v2 = enc[ix.z], v3 = enc[ix.w];
        h4 s = (v0 + v1) + (v2 + v3);                 // v_pk_add_f16 x6
        hold0[i] = make_uint2(pk_bf16(fexp2((float)s.x), fexp2((float)s.y)),
                              pk_bf16(fexp2((float)s.z), fexp2((float)s.w)));
    }
    __syncthreads();  // all P0 reads of enc done
#pragma unroll
    for (int i = 0; i < ROWS_P0 / 1024; ++i) p0[tid + i * 1024] = hold0[i];
    __syncthreads();

    // ---- S1: gather-8 from p0 (b64, exp2-domain), packed-f32 sum trees, log2, hold f16x4 ----
    h4 hold1[4];
#pragma unroll
    for (int i = 0; i < ROWS_S1 / 1024; ++i) {
        int r = tid + i * 1024;
        int4 a = idx1[2 * r], b = idx1[2 * r + 1];
        uint2 u0 = p0[a.x], u1 = p0[a.y], u2 = p0[a.z], u3 = p0[a.w];
        uint2 u4 = p0[b.x], u5 = p0[b.y], u6 = p0[b.z], u7 = p0[b.w];
        f2 ab = (mk2(bf_lo(u0.x), bf_hi(u0.x)) + mk2(bf_lo(u1.x), bf_hi(u1.x))) +
                (mk2(bf_lo(u2.x), bf_hi(u2.x)) + mk2(bf_lo(u3.x), bf_hi(u3.x)));
        ab = ab + ((mk2(bf_lo(u4.x), bf_hi(u4.x)) + mk2(bf_lo(u5.x), bf_hi(u5.x))) +
                   (mk2(bf_lo(u6.x), bf_hi(u6.x)) + mk2(bf_lo(u7.x), bf_hi(u7.x))));
        f2 cd = (mk2(bf_lo(u0.y), bf_hi(u0.y)) + mk2(bf_lo(u1.y), bf_hi(u1.y))) +
                (mk2(bf_lo(u2.y), bf_hi(u2.y)) + mk2(bf_lo(u3.y), bf_hi(u3.y)));
        cd = cd + ((mk2(bf_lo(u4.y), bf_hi(u4.y)) + mk2(bf_lo(u5.y), bf_hi(u5.y))) +
                   (mk2(bf_lo(u6.y), bf_hi(u6.y)) + mk2(bf_lo(u7.y), bf_hi(u7.y))));
        ab = __builtin_elementwise_max(ab, mk2(1e-37f, 1e-37f));
        cd = __builtin_elementwise_max(cd, mk2(1e-37f, 1e-37f));
        h4 o;
        o.x = (_Float16)flog2(ab.x);
        o.y = (_Float16)flog2(ab.y);
        o.z = (_Float16)flog2(cd.x);
        o.w = (_Float16)flog2(cd.y);
        hold1[i] = o;
    }
    __syncthreads();  // all S1 reads of p0 done
#pragma unroll
    for (int i = 0; i < ROWS_S1 / 1024; ++i) s1[tid + i * 1024] = hold1[i];
    __syncthreads();

    // ---- P2: gather-4 from s1 (b64), packed-f16 sum tree, 2^x, hold bf16x4 in regs ----
    uint2 hold2[8];
#pragma unroll
    for (int i = 0; i < ROWS_P2 / 1024; ++i) {
        int r = tid + i * 1024;
        int4 ix = idx2[r];
        h4 v0 = s1[ix.x], v1 = s1[ix.y], v2 = s1[ix.z], v3 = s1[ix.w];
        h4 s = (v0 + v1) + (v2 + v3);                 // v_pk_add_f16 x6
        hold2[i] = make_uint2(pk_bf16(fexp2((float)s.x), fexp2((float)s.y)),
                              pk_bf16(fexp2((float)s.z), fexp2((float)s.w)));
    }
    __syncthreads();  // all P2 reads of s1 done
#pragma unroll
    for (int i = 0; i < ROWS_P2 / 1024; ++i) p2[tid + i * 1024] = hold2[i];
    __syncthreads();

    // ---- S3: gather-8 from p2 (b64), packed-f32 trees, log2 -> ln, direct float4 out ----
#pragma unroll
    for (int i = 0; i < ROWS_S3 / 1024; ++i) {
        int r = tid + i * 1024;
        int4 a = idx3[2 * r], b = idx3[2 * r + 1];
        uint2 u0 = p2[a.x], u1 = p2[a.y], u2 = p2[a.z], u3 = p2[a.w];
        uint2 u4 = p2[b.x], u5 = p2[b.y], u6 = p2[b.z], u7 = p2[b.w];
        f2 ab = (mk2(bf_lo(u0.x), bf_hi(u0.x)) + mk2(bf_lo(u1.x), bf_hi(u1.x))) +
                (mk2(bf_lo(u2.x), bf_hi(u2.x)) + mk2(bf_lo(u3.x), bf_hi(u3.x)));
        ab = ab + ((mk2(bf_lo(u4.x), bf_hi(u4.x)) + mk2(bf_lo(u5.x), bf_hi(u5.x))) +
                   (mk2(bf_lo(u6.x), bf_hi(u6.x)) + mk2(bf_lo(u7.x), bf_hi(u7.x))));
        f2 cd = (mk2(bf_lo(u0.y), bf_hi(u0.y)) + mk2(bf_lo(u1.y), bf_hi(u1.y))) +
                (mk2(bf_lo(u2.y), bf_hi(u2.y)) + mk2(bf_lo(u3.y), bf_hi(u3.y)));
        cd = cd + ((mk2(bf_lo(u4.y), bf_hi(u4.y)) + mk2(bf_lo(u5.y), bf_hi(u5.y))) +
                   (mk2(bf_lo(u6.y), bf_hi(u6.y)) + mk2(bf_lo(u7.y), bf_hi(u7.y))));
        ab = __builtin_elementwise_max(ab, mk2(1e-37f, 1e-37f));
        cd = __builtin_elementwise_max(cd, mk2(1e-37f, 1e-37f));
        float4 o4;
        o4.x = flog2(ab.x) * LN2;
        o4.y = flog2(ab.y) * LN2;
        o4.z = flog2(cd.x) * LN2;
        o4.w = flog2(cd.y) * LN2;
        // direct transposed store: 16B per lane; line-sharing blocks co-reside per XCD
        reinterpret_cast<float4*>(out)[(size_t)r * (BATCH / 4) + swz] = o4;
    }
}

extern "C" void kernel_launch(void* const* d_in, const int* in_sizes, int n_in,
                              void* d_out, int out_size, void* d_ws, size_t ws_size,
                              hipStream_t stream) {
    const float* pos  = (const float*)d_in[0];
    const int4*  idx0 = (const int4*)d_in[1];
    const int4*  idx1 = (const int4*)d_in[2];
    const int4*  idx2 = (const int4*)d_in[3];
    const int4*  idx3 = (const int4*)d_in[4];
    float*       out  = (float*)d_out;
    char*        ws   = (char*)d_ws;

    // ws layout: enc_t [1024 cg][2052] uint2 (16.8 MB)
    uint2* enc_t = (uint2*)ws;

    // 1) fused transpose+encode: pos -> enc_t (all libm lives here, memory-bound)
    encode_kernel<<<dim3(BATCH / 32, NVARS / 32), dim3(32, 8), 0, stream>>>(pos, enc_t);

    // 2) whole circuit in LDS, one block per 4 columns (2 blocks/CU); writes out directly
    pipeline_kernel<<<dim3(BATCH / 4), dim3(1024), 0, stream>>>(enc_t, idx0, idx1, idx2, idx3, out);
}

// Round 12
// 46.045 us; speedup vs baseline: 1.3895x; 1.3895x over previous
//
#include <hip/hip_runtime.h>
#include <math.h>

// Problem geometry (fixed by reference)
#define BATCH   4096
#define NVARS   1024
#define ROWS_P0 8192
#define ROWS_S1 4096
#define ROWS_P2 8192
#define ROWS_S3 2048
#define ENCROWS 2050

#define LOG2E 1.4426950408889634f
#define LN2   0.6931471805599453f

typedef _Float16 h4 __attribute__((ext_vector_type(4)));
typedef float    f2 __attribute__((ext_vector_type(2)));

union HU { h4 h; uint2 u; };

__device__ __forceinline__ float fexp2(float x) { return __builtin_amdgcn_exp2f(x); }
__device__ __forceinline__ float flog2(float x) { return __builtin_amdgcn_logf(x); }

// log2(1 - exp(x)) for x < 0, branchless, native-trans only (~12 VALU).
// x <= -ln2 : 1 - 2^(x*log2e) has no cancellation -> direct.
// x >  -ln2 : 1 - e^-v = v*(1 - v/2 + v^2/6 - v^3/24 + v^4/120), v = -x in (0, ln2);
//             truncation <= 2.2e-4 relative -> ~3e-4 log2 abs, under the f16-storage
//             quantization this feeds (and way under the 0.063 output threshold).
__device__ __forceinline__ float log1mexp_log2(float x) {
    float v = -x;
    float p = 1.0f + v * (-0.5f + v * (0.166666667f + v * (-0.0416666667f + v * 0.00833333333f)));
    float bs = v * p;                       // series value of 1-e^x
    float bd = 1.0f - fexp2(x * LOG2E);     // direct value of 1-e^x
    float arg = (x > -0.6931471805599453f) ? bs : bd;
    return flog2(arg);
}

// Pack two positive f32 (<=1.0) -> bf16x2 in one u32, round-half-up (5 VALU ops).
__device__ __forceinline__ unsigned pk_bf16(float x, float y) {
    unsigned xb = __float_as_uint(x) + 0x8000u;
    unsigned yb = __float_as_uint(y) + 0x8000u;
    return (xb >> 16) | (yb & 0xFFFF0000u);
}
__device__ __forceinline__ float bf_lo(unsigned v) { return __uint_as_float(v << 16); }
__device__ __forceinline__ float bf_hi(unsigned v) { return __uint_as_float(v & 0xFFFF0000u); }
__device__ __forceinline__ f2 mk2(float a, float b) { f2 r; r.x = a; r.y = b; return r; }

// ---------------- single whole-circuit kernel: one block = 4 batch columns ----------------
// Round-12: encode fused back in (fast native-trans log1mexp makes it ~free), pos read
// directly as one float4/thread (lines shared by 8 swz-adjacent blocks -> same-XCD L2).
// Structure as round 11: packed math, register-deferred tables (one live at a time,
// 64 KiB LDS -> 2 blocks/CU), all-b64 LDS gathers serving 4 columns, bijective
// XCD-chunked swizzle for output write-combining.
//   enc : h4[2050]    log2-domain f16x4   | p0/p2 : uint2[8192] EXP2-domain bf16x4
//   s1  : h4[4096]    log2-domain f16x4   (tables overlay one another phase by phase)
// No max-subtraction: p0 in 2^[-80,0], realistic p2 >= 2^-110 > bf16 min-normal.
// fmax floors never trigger legitimately; they only stop pathological 0 -> -inf/NaN.
__global__ __launch_bounds__(1024, 8) void pipeline_kernel(const float* __restrict__ pos,   // [1024][4096]
                                                           const int4* __restrict__ idx0,   // [8192]
                                                           const int4* __restrict__ idx1,   // [4096][2]
                                                           const int4* __restrict__ idx2,   // [8192]
                                                           const int4* __restrict__ idx3,   // [2048][2]
                                                           float* __restrict__ out) {       // [2048][4096]
    __shared__ __align__(16) char pool[65536];
    h4*    enc = reinterpret_cast<h4*>(pool);      // [2050]  (16400 B)
    uint2* p0  = reinterpret_cast<uint2*>(pool);   // [8192]  (65536 B)
    h4*    s1  = reinterpret_cast<h4*>(pool);      // [4096]  (32768 B)
    uint2* p2  = reinterpret_cast<uint2*>(pool);   // [8192]  (65536 B)

    const int tid = threadIdx.x;
    // XCD-chunked bijective swizzle: 1024 blocks, 8 XCDs, 128 blocks/XCD chunk.
    const int bid = blockIdx.x;
    const int swz = ((bid & 7) << 7) | (bid >> 3);
    const int c0 = swz * 4;  // this block's four batch columns

    // ---- E: encode in-pipeline (fast log1mexp), thread tid handles var tid ----
    {
        const float4 a = *reinterpret_cast<const float4*>(pos + (size_t)tid * BATCH + c0);
        HU ep, en;
        ep.h.x = (_Float16)(a.x * LOG2E); ep.h.y = (_Float16)(a.y * LOG2E);
        ep.h.z = (_Float16)(a.z * LOG2E); ep.h.w = (_Float16)(a.w * LOG2E);
        en.h.x = (_Float16)log1mexp_log2(a.x); en.h.y = (_Float16)log1mexp_log2(a.y);
        en.h.z = (_Float16)log1mexp_log2(a.z); en.h.w = (_Float16)log1mexp_log2(a.w);
        uint2* encu = reinterpret_cast<uint2*>(pool);
        encu[2 + 2 * tid] = ep.u;
        encu[3 + 2 * tid] = en.u;
        if (tid == 0) {
            HU ni, z;
            ni.h.x = ni.h.y = ni.h.z = ni.h.w = (_Float16)(-INFINITY);  // row 0: never gathered (idx0>=1)
            z.h.x = z.h.y = z.h.z = z.h.w = (_Float16)0.f;              // row 1: log(1)
            encu[0] = ni.u;
            encu[1] = z.u;
        }
    }
    __syncthreads();

    // ---- P0: gather-4 from enc (b64), packed-f16 sum tree, 2^x, hold bf16x4 in regs ----
    uint2 hold0[8];
#pragma unroll
    for (int i = 0; i < ROWS_P0 / 1024; ++i) {
        int r = tid + i * 1024;
        int4 ix = idx0[r];
        h4 v0 = enc[ix.x], v1 = enc[ix.y], v2 = enc[ix.z], v3 = enc[ix.w];
        h4 s = (v0 + v1) + (v2 + v3);                 // v_pk_add_f16 x6
        hold0[i] = make_uint2(pk_bf16(fexp2((float)s.x), fexp2((float)s.y)),
                              pk_bf16(fexp2((float)s.z), fexp2((float)s.w)));
    }
    __syncthreads();  // all P0 reads of enc done
#pragma unroll
    for (int i = 0; i < ROWS_P0 / 1024; ++i) p0[tid + i * 1024] = hold0[i];
    __syncthreads();

    // ---- S1: gather-8 from p0 (b64, exp2-domain), packed-f32 sum trees, log2, hold f16x4 ----
    h4 hold1[4];
#pragma unroll
    for (int i = 0; i < ROWS_S1 / 1024; ++i) {
        int r = tid + i * 1024;
        int4 a = idx1[2 * r], b = idx1[2 * r + 1];
        uint2 u0 = p0[a.x], u1 = p0[a.y], u2 = p0[a.z], u3 = p0[a.w];
        uint2 u4 = p0[b.x], u5 = p0[b.y], u6 = p0[b.z], u7 = p0[b.w];
        f2 ab = (mk2(bf_lo(u0.x), bf_hi(u0.x)) + mk2(bf_lo(u1.x), bf_hi(u1.x))) +
                (mk2(bf_lo(u2.x), bf_hi(u2.x)) + mk2(bf_lo(u3.x), bf_hi(u3.x)));
        ab = ab + ((mk2(bf_lo(u4.x), bf_hi(u4.x)) + mk2(bf_lo(u5.x), bf_hi(u5.x))) +
                   (mk2(bf_lo(u6.x), bf_hi(u6.x)) + mk2(bf_lo(u7.x), bf_hi(u7.x))));
        f2 cd = (mk2(bf_lo(u0.y), bf_hi(u0.y)) + mk2(bf_lo(u1.y), bf_hi(u1.y))) +
                (mk2(bf_lo(u2.y), bf_hi(u2.y)) + mk2(bf_lo(u3.y), bf_hi(u3.y)));
        cd = cd + ((mk2(bf_lo(u4.y), bf_hi(u4.y)) + mk2(bf_lo(u5.y), bf_hi(u5.y))) +
                   (mk2(bf_lo(u6.y), bf_hi(u6.y)) + mk2(bf_lo(u7.y), bf_hi(u7.y))));
        ab = __builtin_elementwise_max(ab, mk2(1e-37f, 1e-37f));
        cd = __builtin_elementwise_max(cd, mk2(1e-37f, 1e-37f));
        h4 o;
        o.x = (_Float16)flog2(ab.x);
        o.y = (_Float16)flog2(ab.y);
        o.z = (_Float16)flog2(cd.x);
        o.w = (_Float16)flog2(cd.y);
        hold1[i] = o;
    }
    __syncthreads();  // all S1 reads of p0 done
#pragma unroll
    for (int i = 0; i < ROWS_S1 / 1024; ++i) s1[tid + i * 1024] = hold1[i];
    __syncthreads();

    // ---- P2: gather-4 from s1 (b64), packed-f16 sum tree, 2^x, hold bf16x4 in regs ----
    uint2 hold2[8];
#pragma unroll
    for (int i = 0; i < ROWS_P2 / 1024; ++i) {
        int r = tid + i * 1024;
        int4 ix = idx2[r];
        h4 v0 = s1[ix.x], v1 = s1[ix.y], v2 = s1[ix.z], v3 = s1[ix.w];
        h4 s = (v0 + v1) + (v2 + v3);                 // v_pk_add_f16 x6
        hold2[i] = make_uint2(pk_bf16(fexp2((float)s.x), fexp2((float)s.y)),
                              pk_bf16(fexp2((float)s.z), fexp2((float)s.w)));
    }
    __syncthreads();  // all P2 reads of s1 done
#pragma unroll
    for (int i = 0; i < ROWS_P2 / 1024; ++i) p2[tid + i * 1024] = hold2[i];
    __syncthreads();

    // ---- S3: gather-8 from p2 (b64), packed-f32 trees, log2 -> ln, direct float4 out ----
#pragma unroll
    for (int i = 0; i < ROWS_S3 / 1024; ++i) {
        int r = tid + i * 1024;
        int4 a = idx3[2 * r], b = idx3[2 * r + 1];
        uint2 u0 = p2[a.x], u1 = p2[a.y], u2 = p2[a.z], u3 = p2[a.w];
        uint2 u4 = p2[b.x], u5 = p2[b.y], u6 = p2[b.z], u7 = p2[b.w];
        f2 ab = (mk2(bf_lo(u0.x), bf_hi(u0.x)) + mk2(bf_lo(u1.x), bf_hi(u1.x))) +
                (mk2(bf_lo(u2.x), bf_hi(u2.x)) + mk2(bf_lo(u3.x), bf_hi(u3.x)));
        ab = ab + ((mk2(bf_lo(u4.x), bf_hi(u4.x)) + mk2(bf_lo(u5.x), bf_hi(u5.x))) +
                   (mk2(bf_lo(u6.x), bf_hi(u6.x)) + mk2(bf_lo(u7.x), bf_hi(u7.x))));
        f2 cd = (mk2(bf_lo(u0.y), bf_hi(u0.y)) + mk2(bf_lo(u1.y), bf_hi(u1.y))) +
                (mk2(bf_lo(u2.y), bf_hi(u2.y)) + mk2(bf_lo(u3.y), bf_hi(u3.y)));
        cd = cd + ((mk2(bf_lo(u4.y), bf_hi(u4.y)) + mk2(bf_lo(u5.y), bf_hi(u5.y))) +
                   (mk2(bf_lo(u6.y), bf_hi(u6.y)) + mk2(bf_lo(u7.y), bf_hi(u7.y))));
        ab = __builtin_elementwise_max(ab, mk2(1e-37f, 1e-37f));
        cd = __builtin_elementwise_max(cd, mk2(1e-37f, 1e-37f));
        float4 o4;
        o4.x = flog2(ab.x) * LN2;
        o4.y = flog2(ab.y) * LN2;
        o4.z = flog2(cd.x) * LN2;
        o4.w = flog2(cd.y) * LN2;
        // direct transposed store: 16B per lane; line-sharing blocks co-reside per XCD
        reinterpret_cast<float4*>(out)[(size_t)r * (BATCH / 4) + swz] = o4;
    }
}

extern "C" void kernel_launch(void* const* d_in, const int* in_sizes, int n_in,
                              void* d_out, int out_size, void* d_ws, size_t ws_size,
                              hipStream_t stream) {
    const float* pos  = (const float*)d_in[0];
    const int4*  idx0 = (const int4*)d_in[1];
    const int4*  idx1 = (const int4*)d_in[2];
    const int4*  idx2 = (const int4*)d_in[3];
    const int4*  idx3 = (const int4*)d_in[4];
    float*       out  = (float*)d_out;
    (void)d_ws; (void)ws_size;

    // single kernel: whole circuit in LDS, one block per 4 columns (2 blocks/CU)
    pipeline_kernel<<<dim3(BATCH / 4), dim3(1024), 0, stream>>>(pos, idx0, idx1, idx2, idx3, out);
}